// Round 16
// baseline (609.146 us; speedup 1.0000x reference)
//
#include <hip/hip_runtime.h>
#include <hip/hip_bf16.h>

typedef __attribute__((ext_vector_type(4))) float f4;
typedef __attribute__((ext_vector_type(8))) _Float16 h8;
typedef __attribute__((ext_vector_type(4))) _Float16 h4;
typedef __attribute__((ext_vector_type(2))) __fp16 hp2;   // native type of cvt_pkrtz

#define MTOT 131072   // LP*B == B*LQ rows per big GEMM

__device__ __forceinline__ float fast_tanh(float x){
    float e = exp2f(x * 2.8853900817779268f);
    return 1.0f - 2.0f * __builtin_amdgcn_rcpf(e + 1.0f);
}
__device__ __forceinline__ float fast_sigmoid(float x){
    return __builtin_amdgcn_rcpf(1.0f + exp2f(-x * 1.4426950408889634f));
}
__device__ __forceinline__ float wave_reduce_sum(float v){
    #pragma unroll
    for (int off = 32; off; off >>= 1) v += __shfl_down(v, off, 64);
    return v;
}

// ---------- pack both W (fp32 [512][512]) into fp16 MFMA-fragment order ----------
// chunk idx = n16*16 + kt: 1 KB where lane l holds W[n16*16+(l&15)][kt*32+(l>>4)*8 ..+8]
__global__ __launch_bounds__(256) void k_pack_both(
    const float* __restrict__ Wu, const float* __restrict__ Wh,
    _Float16* __restrict__ Pu, _Float16* __restrict__ Ph)
{
    const int g = blockIdx.x;                 // 0..255
    const float* W = (g < 128) ? Wu : Wh;
    _Float16*    P = (g < 128) ? Pu : Ph;
    const int idx = (g & 127) * 4 + (threadIdx.x >> 6);   // 0..511
    const int l = threadIdx.x & 63;
    const int n = (idx >> 4) * 16 + (l & 15);
    const int k = (idx & 15) * 32 + (l >> 4) * 8;
    const float* src = W + n * 512 + k;
    f4 s0 = *(const f4*)(src);
    f4 s1 = *(const f4*)(src + 4);
    h8 v;
    #pragma unroll
    for (int i = 0; i < 4; i++){ v[i] = (_Float16)s0[i]; v[4+i] = (_Float16)s1[i]; }
    *(h8*)(P + (idx << 9) + l * 8) = v;
}

// ---------- big fused GEMM:  s[row] = vb[b] . tanh(A_row @ W^T + add) ----------
// r15 kernel with ONE delta: W read DIRECTLY from the L2-resident fragment-
// packed buffer at its use site (no W LDS). W gets zero cross-wave reuse from
// LDS (each fragment consumed once), so staging it was pure overhead: removes
// 2 gl_lds + 4 ds_read_b128 per lane per kt and empties the barrier's vmcnt
// drain (all loads consumed pre-barrier). A staging unchanged (fp16 reg-stage).
union SMem {
    _Float16 A[2][128][36];   // 18432 B
    _Float16 ep[64][264];     // 33792 B epilogue tile
};
union HU { h8 v; hp2 p[4]; };

template<int MODE>
__global__ __launch_bounds__(512) void k_score_gemm(
    const float* __restrict__ A,
    const _Float16* __restrict__ Wp,
    const float* __restrict__ vb,
    const float* __restrict__ addvec,
    float* __restrict__ spart,
    _Float16* __restrict__ whh)
{
    __shared__ __align__(16) SMem sm;

    const int tid  = threadIdx.x;
    const int lane = tid & 63;
    const int wv   = tid >> 6;      // 0..7
    const int wr   = wv >> 2;       // 0..1  (row half)
    const int wc   = wv & 3;        // 0..3  (col quarter)
    // bijective XCD swizzle: 2048 blocks = 8 XCDs x 256 (verified r11)
    const int swz  = ((blockIdx.x & 7) << 8) | (blockIdx.x >> 3);
    const int mt   = swz >> 1;
    const int nc   = swz & 1;
    const int m0   = mt * 128;
    const int n0   = nc * 256;

    const int lr = lane & 15;       // fragment row/col within 16
    const int kq = lane >> 4;       // k-quarter 0..3

    // A staging: thread t covers A[row=t>>2][(t&3)*8 .. +8) of each 32-k chunk
    const int srow = tid >> 2;
    const int sg   = tid & 3;
    const float* agbase = A + (long)(m0 + srow) * 512 + sg * 8;

    // W fragments: direct from L2-resident packed buffer
    const _Float16* wbase = Wp + ((long)(nc * 16 + wc * 4) << 13) + lane * 8;

    auto cvtA = [&](f4 a0, f4 a1){
        HU u;
        u.p[0] = __builtin_amdgcn_cvt_pkrtz(a0[0], a0[1]);
        u.p[1] = __builtin_amdgcn_cvt_pkrtz(a0[2], a0[3]);
        u.p[2] = __builtin_amdgcn_cvt_pkrtz(a1[0], a1[1]);
        u.p[3] = __builtin_amdgcn_cvt_pkrtz(a1[2], a1[3]);
        return u.v;
    };

    f4 acc[4][4] = {};

    {   // prologue: A(0) into buf 0
        f4 a0 = *(const f4*)(agbase);
        f4 a1 = *(const f4*)(agbase + 4);
        *(h8*)&sm.A[0][srow][sg*8] = cvtA(a0, a1);
    }
    __syncthreads();

    #pragma unroll
    for (int kt = 0; kt < 16; ++kt){
        const int buf = kt & 1;
        f4 a0, a1;
        if (kt < 15){
            const float* p = agbase + (kt + 1) * 32;
            a0 = *(const f4*)p;                  // A prefetch for next iteration
            a1 = *(const f4*)(p + 4);
        }
        // W for current kt: 4x global b128, L2-hit, scoreboard-waited at MFMA
        h8 bf[4];
        #pragma unroll
        for (int ni = 0; ni < 4; ni++)
            bf[ni] = *(const h8*)(wbase + ((ni << 4) + kt) * 512);
        __builtin_amdgcn_sched_barrier(0);

        h8 af[4];
        #pragma unroll
        for (int mi = 0; mi < 4; mi++)
            af[mi] = *(const h8*)&sm.A[buf][wr*64 + mi*16 + lr][kq*8];

        #pragma unroll
        for (int mi = 0; mi < 4; mi++)
            #pragma unroll
            for (int ni = 0; ni < 4; ni++)
                acc[mi][ni] = __builtin_amdgcn_mfma_f32_16x16x32_f16(af[mi], bf[ni], acc[mi][ni], 0, 0, 0);

        if (kt < 15)
            *(h8*)&sm.A[buf ^ 1][srow][sg*8] = cvtA(a0, a1);

        __syncthreads();
    }

    // ---- epilogue (verified r15): LDS tile + row-major score pass ----
    const int jrow = (lane >> 4) * 4;
    for (int hf = 0; hf < 2; ++hf){
        if (wr == hf){
            #pragma unroll
            for (int mi = 0; mi < 4; mi++)
                #pragma unroll
                for (int ni = 0; ni < 4; ni++)
                    #pragma unroll
                    for (int j = 0; j < 4; j++)
                        sm.ep[mi*16 + jrow + j][wc*64 + ni*16 + lr] = (_Float16)acc[mi][ni][j];
        }
        __syncthreads();

        if (MODE == 1 && whh){
            const int row = tid >> 3, seg = tid & 7;
            const int m = m0 + hf*64 + row;
            const _Float16* esrc = &sm.ep[row][seg*32];
            _Float16* gdst = whh + (long)m*512 + n0 + seg*32;
            #pragma unroll
            for (int i = 0; i < 4; i++)
                *(h8*)(gdst + i*8) = *(const h8*)(esrc + i*8);
        }

        {   // score: thread t owns row t>>3, 32 strided cols, 8-lane tree reduce
            const int row = tid >> 3;            // 0..63
            const int sub = tid & 7;
            const int m = m0 + hf*64 + row;
            const int b = (MODE == 0) ? (m >> 12) : (m & 31);
            float p = 0.f;
            #pragma unroll
            for (int j = 0; j < 8; ++j){
                const int col = sub*4 + j*32;
                h4 hv = *(const h4*)&sm.ep[row][col];
                f4 vbv = *(const f4*)&vb[b*512 + n0 + col];
                f4 adv;
                if (MODE == 0) adv = *(const f4*)&addvec[n0 + col];
                else           adv = *(const f4*)&addvec[b*512 + n0 + col];
                #pragma unroll
                for (int i = 0; i < 4; i++)
                    p += fast_tanh((float)hv[i] + adv[i]) * vbv[i];
            }
            p += __shfl_down(p, 4, 8);
            p += __shfl_down(p, 2, 8);
            p += __shfl_down(p, 1, 8);
            if (sub == 0){
                const int sIdx = (MODE == 0) ? m : (((m & 31) << 12) | (m >> 5));
                spart[nc*MTOT + sIdx] = p;
            }
        }
        __syncthreads();
    }
}

// ---------- softmax over 4096, summing NP partial-score arrays (unrolled) ----------
template<int NP>
__global__ __launch_bounds__(256) void k_softmax(const float* __restrict__ s,
        float* __restrict__ out)
{
    __shared__ float red[8];
    __shared__ float bcast[2];
    const int b = blockIdx.x, t = threadIdx.x;
    const int wv = t >> 6, lane = t & 63;
    float vals[16];
    float mx = -3.0e38f;
    #pragma unroll
    for (int i = 0; i < 16; i++){
        float v = s[b*4096 + t + i*256];
        #pragma unroll
        for (int p = 1; p < NP; p++) v += s[p*MTOT + b*4096 + t + i*256];
        vals[i] = v;
        mx = fmaxf(mx, v);
    }
    #pragma unroll
    for (int off = 32; off; off >>= 1) mx = fmaxf(mx, __shfl_down(mx, off, 64));
    if (lane == 0) red[wv] = mx;
    __syncthreads();
    if (t == 0) bcast[0] = fmaxf(fmaxf(red[0], red[1]), fmaxf(red[2], red[3]));
    __syncthreads();
    const float gmax = bcast[0];
    float sum = 0.f;
    #pragma unroll
    for (int i = 0; i < 16; i++){
        vals[i] = exp2f((vals[i] - gmax) * 1.4426950408889634f);
        sum += vals[i];
    }
    sum = wave_reduce_sum(sum);
    if (lane == 0) red[wv] = sum;
    __syncthreads();
    if (t == 0) bcast[1] = red[0] + red[1] + red[2] + red[3];
    __syncthreads();
    const float inv = 1.0f / bcast[1];
    #pragma unroll
    for (int i = 0; i < 16; i++) out[b*4096 + t + i*256] = vals[i] * inv;
}

// ---------- weighted row-sum: part[ch][b][d] = sum_q wts[b][q] * X[row(q,b)][d] ----------
__global__ __launch_bounds__(512) void k_weighted_rowsum(
    const float* __restrict__ wts, const float* __restrict__ X,
    float* __restrict__ part, int mode)
{
    const int b = blockIdx.x, ch = blockIdx.y, d = threadIdx.x;
    float acc = 0.f;
    const int q0 = ch * 128;
    for (int q = q0; q < q0 + 128; ++q){
        const float w = wts[b*4096 + q];
        if (fabsf(w) > 1e-20f){   // block-uniform branch; softmax weights mostly 0
            const float* xp = (mode == 0) ? (X + ((long)(b*4096 + q) * 512) + d)
                                          : (X + ((long)(q*32 + b) * 512) + d);
            acc += w * xp[0];
        }
    }
    part[(ch*32 + b)*512 + d] = acc;
}

__global__ void k_reduce_part(const float* __restrict__ part, float* __restrict__ out){
    const int b = blockIdx.x, d = threadIdx.x;
    float s = 0.f;
    #pragma unroll
    for (int ch = 0; ch < 32; ++ch) s += part[(ch*32 + b)*512 + d];
    out[b*512 + d] = s;
}

// ---------- small matvec: out[b][row] = W[row,:] . x[b,:] (+bias), K=512 ----------
__global__ __launch_bounds__(256) void k_matvec(
    const float* __restrict__ W, const float* __restrict__ x,
    const float* __restrict__ bias, float* __restrict__ out, int N)
{
    __shared__ float xs[512];
    const int b = blockIdx.x, t = threadIdx.x;
    xs[t] = x[b*512 + t];
    xs[t + 256] = x[b*512 + 256 + t];
    __syncthreads();
    const int wv = t >> 6, lane = t & 63;
    f4 x0 = *(const f4*)&xs[lane*8];
    f4 x1 = *(const f4*)&xs[lane*8 + 4];
    const int rbase = blockIdx.y*32 + wv*8;
    for (int rr = 0; rr < 8; ++rr){
        const int row = rbase + rr;
        const float* wp = W + (long)row*512 + lane*8;
        f4 w0 = *(const f4*)wp;
        f4 w1 = *(const f4*)(wp + 4);
        float p = w0[0]*x0[0] + w0[1]*x0[1] + w0[2]*x0[2] + w0[3]*x0[3]
                + w1[0]*x1[0] + w1[1]*x1[1] + w1[2]*x1[2] + w1[3]*x1[3];
        p = wave_reduce_sum(p);
        if (lane == 0) out[b*N + row] = p + (bias ? bias[row] : 0.f);
    }
}

// ---------- GRU gates ----------
__global__ void k_gru(const float* __restrict__ gi, const float* __restrict__ gh,
                      const float* __restrict__ r, float* __restrict__ r2)
{
    const int b = blockIdx.x, d = threadIdx.x;
    const float* gib = gi + b*1536;
    const float* ghb = gh + b*1536;
    const float rg = fast_sigmoid(gib[d]        + ghb[d]);
    const float z  = fast_sigmoid(gib[512 + d]  + ghb[512 + d]);
    const float n  = fast_tanh   (gib[1024 + d] + rg * ghb[1024 + d]);
    r2[b*512 + d] = (1.f - z)*n + z*r[b*512 + d];
}

// ---------- second h-attention scores from cached Whh16 ----------
__global__ __launch_bounds__(256) void k_t2(const _Float16* __restrict__ whh,
        const float* __restrict__ vb, const float* __restrict__ ra2, float* __restrict__ t2)
{
    const int wv = threadIdx.x >> 6, lane = threadIdx.x & 63;
    const int mbase = blockIdx.x*32 + wv*8;
    for (int rr = 0; rr < 8; ++rr){
        const int m = mbase + rr;
        const int b = m & 31;
        h8 hv = *(const h8*)(whh + (long)m*512 + lane*8);
        const float* rp  = ra2 + b*512 + lane*8;
        const float* vbp = vb  + b*512 + lane*8;
        float p = 0.f;
        #pragma unroll
        for (int i = 0; i < 8; i++)
            p += fast_tanh((float)hv[i] + rp[i]) * vbp[i];
        p = wave_reduce_sum(p);
        if (lane == 0) t2[((m & 31) << 12) | (m >> 5)] = p;
    }
}

extern "C" void kernel_launch(void* const* d_in, const int* in_sizes, int n_in,
                              void* d_out, int out_size, void* d_ws, size_t ws_size,
                              hipStream_t stream)
{
    const float* h_    = (const float*)d_in[0];
    const float* u_    = (const float*)d_in[1];
    const float* vb    = (const float*)d_in[2];   // (B,D,1) contiguous == (B,D)
    const float* Wu_w  = (const float*)d_in[3];
    const float* Wu_b  = (const float*)d_in[4];
    const float* Wh_w  = (const float*)d_in[5];
    const float* Wha_w = (const float*)d_in[6];
    const float* W_ih  = (const float*)d_in[7];
    const float* W_hh  = (const float*)d_in[8];
    const float* b_ih  = (const float*)d_in[9];
    const float* b_hh  = (const float*)d_in[10];
    float* out = (float*)d_out;

    char* ws = (char*)d_ws;
    float*    spart = (float*)(ws + 0);            // [2][131072] = 1 MB
    float*    tpart = (float*)(ws + 1048576);      // [2][131072] = 1 MB
    float*    part  = (float*)(ws + 2097152);      // [32][32][512] = 2 MB
    float*    a_    = (float*)(ws + 4194304);      // [32][4096] = 512 KB
    _Float16* Wpu   = (_Float16*)(ws + 4718592);   // 512x512 fp16, fragment-packed
    _Float16* Wph   = (_Float16*)(ws + 5242880);
    float*    r_    = (float*)(ws + 5767168);      // [32][512] each
    float*    ra1   = (float*)(ws + 5832704);
    float*    c_    = (float*)(ws + 5898240);
    float*    r2    = (float*)(ws + 5963776);
    float*    ra2   = (float*)(ws + 6029312);
    float*    gi    = (float*)(ws + 6094848);      // [32][1536]
    float*    gh    = (float*)(ws + 6291456);
    _Float16* whh   = (_Float16*)(ws + 8388608);   // [131072][512] fp16 = 128 MB
    const bool big = ws_size >= (size_t)8388608 + (size_t)MTOT * 512 * 2;

    k_pack_both<<<256, 256, 0, stream>>>(Wu_w, Wh_w, Wpu, Wph);

    // u-side attention -> a -> r -> ra1
    k_score_gemm<0><<<2048, 512, 0, stream>>>(u_, Wpu, vb, Wu_b, spart, nullptr);
    k_softmax<2><<<32, 256, 0, stream>>>(spart, a_);
    k_weighted_rowsum<<<dim3(32, 32), 512, 0, stream>>>(a_, u_, part, 0);
    k_reduce_part<<<32, 512, 0, stream>>>(part, r_);
    k_matvec<<<dim3(32, 16), 256, 0, stream>>>(Wha_w, r_, nullptr, ra1, 512);

    // h-side attention #1 (stores Whh_proj fp16) -> p1
    k_score_gemm<1><<<2048, 512, 0, stream>>>(h_, Wph, vb, ra1, tpart, big ? whh : nullptr);
    k_softmax<2><<<32, 256, 0, stream>>>(tpart, out);                     // p1

    // c = p1 . h ; GRU ; ra2
    k_weighted_rowsum<<<dim3(32, 32), 512, 0, stream>>>(out, h_, part, 1);
    k_reduce_part<<<32, 512, 0, stream>>>(part, c_);
    k_matvec<<<dim3(32, 48), 256, 0, stream>>>(W_ih, c_, b_ih, gi, 1536);
    k_matvec<<<dim3(32, 48), 256, 0, stream>>>(W_hh, r_, b_hh, gh, 1536);
    k_gru<<<32, 512, 0, stream>>>(gi, gh, r_, r2);
    k_matvec<<<dim3(32, 16), 256, 0, stream>>>(Wha_w, r2, nullptr, ra2, 512);

    // h-side attention #2 -> p2
    if (big){
        k_t2<<<4096, 256, 0, stream>>>(whh, vb, ra2, tpart);
        k_softmax<1><<<32, 256, 0, stream>>>(tpart, out + MTOT);
    } else {
        k_score_gemm<2><<<2048, 512, 0, stream>>>(h_, Wph, vb, ra2, tpart, nullptr);
        k_softmax<2><<<32, 256, 0, stream>>>(tpart, out + MTOT);
    }
}

// Round 17
// 482.520 us; speedup vs baseline: 1.2624x; 1.2624x over previous
//
#include <hip/hip_runtime.h>
#include <hip/hip_bf16.h>

typedef __attribute__((ext_vector_type(4))) float f4;
typedef __attribute__((ext_vector_type(8))) _Float16 h8;
typedef __attribute__((ext_vector_type(4))) _Float16 h4;
typedef __attribute__((ext_vector_type(2))) __fp16 hp2;   // native type of cvt_pkrtz

#define MTOT 131072   // LP*B == B*LQ rows per big GEMM

__device__ __forceinline__ float fast_tanh(float x){
    float e = exp2f(x * 2.8853900817779268f);
    return 1.0f - 2.0f * __builtin_amdgcn_rcpf(e + 1.0f);
}
__device__ __forceinline__ float fast_sigmoid(float x){
    return __builtin_amdgcn_rcpf(1.0f + exp2f(-x * 1.4426950408889634f));
}
__device__ __forceinline__ float wave_reduce_sum(float v){
    #pragma unroll
    for (int off = 32; off; off >>= 1) v += __shfl_down(v, off, 64);
    return v;
}

__device__ __forceinline__ void gl_lds16(const void* g, void* l){
    __builtin_amdgcn_global_load_lds(
        (const __attribute__((address_space(1))) void*)g,
        (__attribute__((address_space(3))) void*)l, 16, 0, 0);
}

// ---------- pack both W (fp32 [512][512]) into fp16 MFMA-fragment order ----------
// chunk idx = n16*16 + kt: 1 KB where lane l holds W[n16*16+(l&15)][kt*32+(l>>4)*8 ..+8]
__global__ __launch_bounds__(256) void k_pack_both(
    const float* __restrict__ Wu, const float* __restrict__ Wh,
    _Float16* __restrict__ Pu, _Float16* __restrict__ Ph)
{
    const int g = blockIdx.x;                 // 0..255
    const float* W = (g < 128) ? Wu : Wh;
    _Float16*    P = (g < 128) ? Pu : Ph;
    const int idx = (g & 127) * 4 + (threadIdx.x >> 6);   // 0..511
    const int l = threadIdx.x & 63;
    const int n = (idx >> 4) * 16 + (l & 15);
    const int k = (idx & 15) * 32 + (l >> 4) * 8;
    const float* src = W + n * 512 + k;
    f4 s0 = *(const f4*)(src);
    f4 s1 = *(const f4*)(src + 4);
    h8 v;
    #pragma unroll
    for (int i = 0; i < 4; i++){ v[i] = (_Float16)s0[i]; v[4+i] = (_Float16)s1[i]; }
    *(h8*)(P + (idx << 9) + l * 8) = v;
}

// ---------- big fused GEMM:  s[row] = vb[b] . tanh(A_row @ W^T + add) ----------
// BEST CONFIG (r15, 483 us total): 512 thr, 128x256 tile, fp16-A reg-stage +
// W gload_lds double-buffer, drain barrier, XCD swizzle, row-major score pass.
// RAZOR EDGE: 64 VGPR + 64 AGPR = exactly 128 unified regs -> 4 waves/SIMD.
// r16 proved +4 VGPR (W-direct addressing) halves occupancy -> +46% time.
union SMem {
    struct { _Float16 A[2][128][36]; _Float16 W[2][8192]; } st;  // 18432 + 32768 B
    _Float16 ep[64][264];                                        // 33792 B
};
union HU { h8 v; hp2 p[4]; };

template<int MODE>
__global__ __launch_bounds__(512) void k_score_gemm(
    const float* __restrict__ A,
    const _Float16* __restrict__ Wp,
    const float* __restrict__ vb,
    const float* __restrict__ addvec,
    float* __restrict__ spart,
    _Float16* __restrict__ whh)
{
    __shared__ __align__(16) SMem sm;

    const int tid  = threadIdx.x;
    const int lane = tid & 63;
    const int wv   = tid >> 6;      // 0..7
    const int wr   = wv >> 2;       // 0..1  (row half)
    const int wc   = wv & 3;        // 0..3  (col quarter)
    // bijective XCD swizzle: 2048 blocks = 8 XCDs x 256 (verified r11)
    const int swz  = ((blockIdx.x & 7) << 8) | (blockIdx.x >> 3);
    const int mt   = swz >> 1;
    const int nc   = swz & 1;
    const int m0   = mt * 128;
    const int n0   = nc * 256;

    const int lr = lane & 15;       // fragment row/col within 16
    const int kq = lane >> 4;       // k-quarter 0..3

    // A staging: thread t covers A[row=t>>2][(t&3)*8 .. +8) of each 32-k chunk
    const int srow = tid >> 2;
    const int sg   = tid & 3;
    const float* agbase = A + (long)(m0 + srow) * 512 + sg * 8;

    auto stageW = [&](int kt, int buf){
        #pragma unroll
        for (int i = 0; i < 2; i++){
            const int chunk = i*8 + wv;                       // 16 chunks of 1 KB
            const _Float16* g = Wp + ((long)((nc*16 + chunk)*16 + kt))*512 + lane*8;
            char* l = (char*)&sm.st.W[0][0] + buf*16384 + chunk*1024;
            gl_lds16(g, l);
        }
    };
    auto cvtA = [&](f4 a0, f4 a1){
        HU u;
        u.p[0] = __builtin_amdgcn_cvt_pkrtz(a0[0], a0[1]);
        u.p[1] = __builtin_amdgcn_cvt_pkrtz(a0[2], a0[3]);
        u.p[2] = __builtin_amdgcn_cvt_pkrtz(a1[0], a1[1]);
        u.p[3] = __builtin_amdgcn_cvt_pkrtz(a1[2], a1[3]);
        return u.v;
    };

    f4 acc[4][4] = {};

    {   // prologue: A(0) + W(0) into buf 0
        f4 a0 = *(const f4*)(agbase);
        f4 a1 = *(const f4*)(agbase + 4);
        stageW(0, 0);
        *(h8*)&sm.st.A[0][srow][sg*8] = cvtA(a0, a1);
    }
    __syncthreads();

    for (int kt = 0; kt < 16; ++kt){
        const int buf = kt & 1;
        f4 a0, a1;
        if (kt < 15){
            const float* p = agbase + (kt + 1) * 32;
            a0 = *(const f4*)p;                  // A loads FIRST (oldest in queue:
            a1 = *(const f4*)(p + 4);            //  auto-wait before cvt = vmcnt(2))
            stageW(kt + 1, buf ^ 1);             // W gloads stay in flight past cvt
        }
        __builtin_amdgcn_sched_barrier(0);

        h8 af[4];
        #pragma unroll
        for (int mi = 0; mi < 4; mi++)
            af[mi] = *(const h8*)&sm.st.A[buf][wr*64 + mi*16 + lr][kq*8];
        const _Float16* Wb = &sm.st.W[0][0] + buf*8192;
        h8 bf[4];
        #pragma unroll
        for (int ni = 0; ni < 4; ni++)
            bf[ni] = *(const h8*)(Wb + (wc*4 + ni)*512 + lane*8);

        #pragma unroll
        for (int mi = 0; mi < 4; mi++)
            #pragma unroll
            for (int ni = 0; ni < 4; ni++)
                acc[mi][ni] = __builtin_amdgcn_mfma_f32_16x16x32_f16(af[mi], bf[ni], acc[mi][ni], 0, 0, 0);

        if (kt < 15)
            *(h8*)&sm.st.A[buf ^ 1][srow][sg*8] = cvtA(a0, a1);

        __syncthreads();
    }

    // ---- epilogue: LDS tile reuse; row-major score pass (3 shfl vs 96) ----
    const int jrow = (lane >> 4) * 4;
    for (int hf = 0; hf < 2; ++hf){
        if (wr == hf){
            #pragma unroll
            for (int mi = 0; mi < 4; mi++)
                #pragma unroll
                for (int ni = 0; ni < 4; ni++)
                    #pragma unroll
                    for (int j = 0; j < 4; j++)
                        sm.ep[mi*16 + jrow + j][wc*64 + ni*16 + lr] = (_Float16)acc[mi][ni][j];
        }
        __syncthreads();

        if (MODE == 1 && whh){
            const int row = tid >> 3, seg = tid & 7;
            const int m = m0 + hf*64 + row;
            const _Float16* esrc = &sm.ep[row][seg*32];
            _Float16* gdst = whh + (long)m*512 + n0 + seg*32;
            #pragma unroll
            for (int i = 0; i < 4; i++)
                *(h8*)(gdst + i*8) = *(const h8*)(esrc + i*8);
        }

        {   // score: thread t owns row t>>3, 32 strided cols (bank-spread),
            // 8-lane tree reduction (width-8 shfl x3)
            const int row = tid >> 3;            // 0..63
            const int sub = tid & 7;
            const int m = m0 + hf*64 + row;
            const int b = (MODE == 0) ? (m >> 12) : (m & 31);
            float p = 0.f;
            #pragma unroll
            for (int j = 0; j < 8; ++j){
                const int col = sub*4 + j*32;
                h4 hv = *(const h4*)&sm.ep[row][col];
                f4 vbv = *(const f4*)&vb[b*512 + n0 + col];
                f4 adv;
                if (MODE == 0) adv = *(const f4*)&addvec[n0 + col];
                else           adv = *(const f4*)&addvec[b*512 + n0 + col];
                #pragma unroll
                for (int i = 0; i < 4; i++)
                    p += fast_tanh((float)hv[i] + adv[i]) * vbv[i];
            }
            p += __shfl_down(p, 4, 8);
            p += __shfl_down(p, 2, 8);
            p += __shfl_down(p, 1, 8);
            if (sub == 0){
                const int sIdx = (MODE == 0) ? m : (((m & 31) << 12) | (m >> 5));
                spart[nc*MTOT + sIdx] = p;
            }
        }
        __syncthreads();
    }
}

// ---------- softmax over 4096, summing NP partial-score arrays (unrolled) ----------
template<int NP>
__global__ __launch_bounds__(256) void k_softmax(const float* __restrict__ s,
        float* __restrict__ out)
{
    __shared__ float red[8];
    __shared__ float bcast[2];
    const int b = blockIdx.x, t = threadIdx.x;
    const int wv = t >> 6, lane = t & 63;
    float vals[16];
    float mx = -3.0e38f;
    #pragma unroll
    for (int i = 0; i < 16; i++){
        float v = s[b*4096 + t + i*256];
        #pragma unroll
        for (int p = 1; p < NP; p++) v += s[p*MTOT + b*4096 + t + i*256];
        vals[i] = v;
        mx = fmaxf(mx, v);
    }
    #pragma unroll
    for (int off = 32; off; off >>= 1) mx = fmaxf(mx, __shfl_down(mx, off, 64));
    if (lane == 0) red[wv] = mx;
    __syncthreads();
    if (t == 0) bcast[0] = fmaxf(fmaxf(red[0], red[1]), fmaxf(red[2], red[3]));
    __syncthreads();
    const float gmax = bcast[0];
    float sum = 0.f;
    #pragma unroll
    for (int i = 0; i < 16; i++){
        vals[i] = exp2f((vals[i] - gmax) * 1.4426950408889634f);
        sum += vals[i];
    }
    sum = wave_reduce_sum(sum);
    if (lane == 0) red[wv] = sum;
    __syncthreads();
    if (t == 0) bcast[1] = red[0] + red[1] + red[2] + red[3];
    __syncthreads();
    const float inv = 1.0f / bcast[1];
    #pragma unroll
    for (int i = 0; i < 16; i++) out[b*4096 + t + i*256] = vals[i] * inv;
}

// ---------- weighted row-sum: part[ch][b][d] = sum_q wts[b][q] * X[row(q,b)][d] ----------
__global__ __launch_bounds__(512) void k_weighted_rowsum(
    const float* __restrict__ wts, const float* __restrict__ X,
    float* __restrict__ part, int mode)
{
    const int b = blockIdx.x, ch = blockIdx.y, d = threadIdx.x;
    float acc = 0.f;
    const int q0 = ch * 128;
    for (int q = q0; q < q0 + 128; ++q){
        const float w = wts[b*4096 + q];
        if (fabsf(w) > 1e-20f){   // block-uniform branch; softmax weights mostly 0
            const float* xp = (mode == 0) ? (X + ((long)(b*4096 + q) * 512) + d)
                                          : (X + ((long)(q*32 + b) * 512) + d);
            acc += w * xp[0];
        }
    }
    part[(ch*32 + b)*512 + d] = acc;
}

__global__ void k_reduce_part(const float* __restrict__ part, float* __restrict__ out){
    const int b = blockIdx.x, d = threadIdx.x;
    float s = 0.f;
    #pragma unroll
    for (int ch = 0; ch < 32; ++ch) s += part[(ch*32 + b)*512 + d];
    out[b*512 + d] = s;
}

// ---------- small matvec: out[b][row] = W[row,:] . x[b,:] (+bias), K=512 ----------
__global__ __launch_bounds__(256) void k_matvec(
    const float* __restrict__ W, const float* __restrict__ x,
    const float* __restrict__ bias, float* __restrict__ out, int N)
{
    __shared__ float xs[512];
    const int b = blockIdx.x, t = threadIdx.x;
    xs[t] = x[b*512 + t];
    xs[t + 256] = x[b*512 + 256 + t];
    __syncthreads();
    const int wv = t >> 6, lane = t & 63;
    f4 x0 = *(const f4*)&xs[lane*8];
    f4 x1 = *(const f4*)&xs[lane*8 + 4];
    const int rbase = blockIdx.y*32 + wv*8;
    for (int rr = 0; rr < 8; ++rr){
        const int row = rbase + rr;
        const float* wp = W + (long)row*512 + lane*8;
        f4 w0 = *(const f4*)wp;
        f4 w1 = *(const f4*)(wp + 4);
        float p = w0[0]*x0[0] + w0[1]*x0[1] + w0[2]*x0[2] + w0[3]*x0[3]
                + w1[0]*x1[0] + w1[1]*x1[1] + w1[2]*x1[2] + w1[3]*x1[3];
        p = wave_reduce_sum(p);
        if (lane == 0) out[b*N + row] = p + (bias ? bias[row] : 0.f);
    }
}

// ---------- GRU gates ----------
__global__ void k_gru(const float* __restrict__ gi, const float* __restrict__ gh,
                      const float* __restrict__ r, float* __restrict__ r2)
{
    const int b = blockIdx.x, d = threadIdx.x;
    const float* gib = gi + b*1536;
    const float* ghb = gh + b*1536;
    const float rg = fast_sigmoid(gib[d]        + ghb[d]);
    const float z  = fast_sigmoid(gib[512 + d]  + ghb[512 + d]);
    const float n  = fast_tanh   (gib[1024 + d] + rg * ghb[1024 + d]);
    r2[b*512 + d] = (1.f - z)*n + z*r[b*512 + d];
}

// ---------- second h-attention scores from cached Whh16 ----------
__global__ __launch_bounds__(256) void k_t2(const _Float16* __restrict__ whh,
        const float* __restrict__ vb, const float* __restrict__ ra2, float* __restrict__ t2)
{
    const int wv = threadIdx.x >> 6, lane = threadIdx.x & 63;
    const int mbase = blockIdx.x*32 + wv*8;
    for (int rr = 0; rr < 8; ++rr){
        const int m = mbase + rr;
        const int b = m & 31;
        h8 hv = *(const h8*)(whh + (long)m*512 + lane*8);
        const float* rp  = ra2 + b*512 + lane*8;
        const float* vbp = vb  + b*512 + lane*8;
        float p = 0.f;
        #pragma unroll
        for (int i = 0; i < 8; i++)
            p += fast_tanh((float)hv[i] + rp[i]) * vbp[i];
        p = wave_reduce_sum(p);
        if (lane == 0) t2[((m & 31) << 12) | (m >> 5)] = p;
    }
}

extern "C" void kernel_launch(void* const* d_in, const int* in_sizes, int n_in,
                              void* d_out, int out_size, void* d_ws, size_t ws_size,
                              hipStream_t stream)
{
    const float* h_    = (const float*)d_in[0];
    const float* u_    = (const float*)d_in[1];
    const float* vb    = (const float*)d_in[2];   // (B,D,1) contiguous == (B,D)
    const float* Wu_w  = (const float*)d_in[3];
    const float* Wu_b  = (const float*)d_in[4];
    const float* Wh_w  = (const float*)d_in[5];
    const float* Wha_w = (const float*)d_in[6];
    const float* W_ih  = (const float*)d_in[7];
    const float* W_hh  = (const float*)d_in[8];
    const float* b_ih  = (const float*)d_in[9];
    const float* b_hh  = (const float*)d_in[10];
    float* out = (float*)d_out;

    char* ws = (char*)d_ws;
    float*    spart = (float*)(ws + 0);            // [2][131072] = 1 MB
    float*    tpart = (float*)(ws + 1048576);      // [2][131072] = 1 MB
    float*    part  = (float*)(ws + 2097152);      // [32][32][512] = 2 MB
    float*    a_    = (float*)(ws + 4194304);      // [32][4096] = 512 KB
    _Float16* Wpu   = (_Float16*)(ws + 4718592);   // 512x512 fp16, fragment-packed
    _Float16* Wph   = (_Float16*)(ws + 5242880);
    float*    r_    = (float*)(ws + 5767168);      // [32][512] each
    float*    ra1   = (float*)(ws + 5832704);
    float*    c_    = (float*)(ws + 5898240);
    float*    r2    = (float*)(ws + 5963776);
    float*    ra2   = (float*)(ws + 6029312);
    float*    gi    = (float*)(ws + 6094848);      // [32][1536]
    float*    gh    = (float*)(ws + 6291456);
    _Float16* whh   = (_Float16*)(ws + 8388608);   // [131072][512] fp16 = 128 MB
    const bool big = ws_size >= (size_t)8388608 + (size_t)MTOT * 512 * 2;

    k_pack_both<<<256, 256, 0, stream>>>(Wu_w, Wh_w, Wpu, Wph);

    // u-side attention -> a -> r -> ra1
    k_score_gemm<0><<<2048, 512, 0, stream>>>(u_, Wpu, vb, Wu_b, spart, nullptr);
    k_softmax<2><<<32, 256, 0, stream>>>(spart, a_);
    k_weighted_rowsum<<<dim3(32, 32), 512, 0, stream>>>(a_, u_, part, 0);
    k_reduce_part<<<32, 512, 0, stream>>>(part, r_);
    k_matvec<<<dim3(32, 16), 256, 0, stream>>>(Wha_w, r_, nullptr, ra1, 512);

    // h-side attention #1 (stores Whh_proj fp16) -> p1
    k_score_gemm<1><<<2048, 512, 0, stream>>>(h_, Wph, vb, ra1, tpart, big ? whh : nullptr);
    k_softmax<2><<<32, 256, 0, stream>>>(tpart, out);                     // p1

    // c = p1 . h ; GRU ; ra2
    k_weighted_rowsum<<<dim3(32, 32), 512, 0, stream>>>(out, h_, part, 1);
    k_reduce_part<<<32, 512, 0, stream>>>(part, c_);
    k_matvec<<<dim3(32, 48), 256, 0, stream>>>(W_ih, c_, b_ih, gi, 1536);
    k_matvec<<<dim3(32, 48), 256, 0, stream>>>(W_hh, r_, b_hh, gh, 1536);
    k_gru<<<32, 512, 0, stream>>>(gi, gh, r_, r2);
    k_matvec<<<dim3(32, 16), 256, 0, stream>>>(Wha_w, r2, nullptr, ra2, 512);

    // h-side attention #2 -> p2
    if (big){
        k_t2<<<4096, 256, 0, stream>>>(whh, vb, ra2, tpart);
        k_softmax<1><<<32, 256, 0, stream>>>(tpart, out + MTOT);
    } else {
        k_score_gemm<2><<<2048, 512, 0, stream>>>(h_, Wph, vb, ra2, tpart, nullptr);
        k_softmax<2><<<32, 256, 0, stream>>>(tpart, out + MTOT);
    }
}